// Round 6
// baseline (682.355 us; speedup 1.0000x reference)
//
#include <hip/hip_runtime.h>

// Sparsemax attention: B=8, L=1024, S=1024, H=16, E=64, D=64, fp32 in/out.
// r15 = K-RESIDENT restructure. Evidence (r9..r14): dur floors at ~330us
// regardless of residency (2/3/4 blocks/CU) and VALU work level -> floor is
// the barrier-staged tile loop (each K elem staged 32x; 16 barriers/block;
// stage->vmcnt->cvt->ds_write->barrier convoy per tile).
// New shape: grid 256 (1 block/CU, 2 blocks per bh), block owns 512 L-rows.
//  - Whole fp16 K slab (128KB) staged into LDS ONCE per block (16x less
//    staging work globally).
//  - 16 chunks of 32 rows; per chunk: {reset+Q-stage, barrier, 8 j-tiles
//    with NO barriers/staging (ds_read frags + MFMA + filter), barrier,
//    Newton + compact + gather (code identical to r14), barrier}.
//  - LDS total 153472B (<160K HW max; 128KB+ static precedent: m201).
// r14 lessons kept: shared row-max filter, packed u32 lists, support
// compaction, CAP=112/SUP=24, no loop-carried prefetch regs.

typedef _Float16 f16x8 __attribute__((ext_vector_type(8)));
typedef float    f32x4 __attribute__((ext_vector_type(4)));

constexpr int kB = 8, kL = 1024, kS = 1024, kH = 16, kE = 64, kD = 64;
constexpr int LT   = 32;          // L rows per chunk (2 query-groups of 16)
constexpr int JT   = 128;         // S cols per j-tile
constexpr int NCH  = 16;          // chunks per block (512 rows)
constexpr int CAP  = 112;         // candidate capacity per row
constexpr int KMAX = CAP / 16;    // Newton regs per lane (16 lanes per row)
constexpr int SUP  = 24;          // compacted support capacity per row

__device__ __forceinline__ float pk2(float a, float b) {
  auto h = __builtin_amdgcn_cvt_pkrtz(a, b);
  return __builtin_bit_cast(float, h);
}

__device__ __forceinline__ float unpack_z(unsigned v) {
  return __uint_as_float((v & ~1023u) | 512u);  // midpoint restore
}

__global__ __launch_bounds__(512, 2)
void sparsemax_attn(const float* __restrict__ Q, const float* __restrict__ K,
                    const float* __restrict__ V, float* __restrict__ O) {
  __shared__ float4   Ksh[kS * 8];      // 128 KB: WHOLE fp16 K slab, slot^(row&7)
  __shared__ float4   Qsh[LT * 8];      //   4 KB fp16 Q chunk (scale folded)
  __shared__ unsigned lists[LT * CAP];  //  14 KB packed (z-hi22 | j10)
  __shared__ unsigned sup_s[LT][SUP];   //   3 KB compacted support entries
  __shared__ int      cnt_s[LT];
  __shared__ int      cnt2_s[LT];
  __shared__ float    rmax_s[LT][4];
  __shared__ float    tau_s[LT];

  const int t = threadIdx.x, lane = t & 63, w = t >> 6;
  const int qg = w >> 2, jg = w & 3;       // query-group, j-group
  const int li = lane & 15, g = lane >> 4;
  const int myrow = qg * 16 + li;          // chunk-local row this lane serves

  const int id  = blockIdx.x;              // 256 blocks: 2 per (b,h)
  const int bh  = id >> 1;
  const int b   = bh >> 4, h = bh & 15;
  const int Lbase = (id & 1) * (kL / 2);   // 512-row half owned by this block

  const float* Kbh = K + ((size_t)b * kS * kH + h) * kE;
  const float* Vb  = V + ((size_t)b * kS * kH + h) * kD;

  // ---- stage the WHOLE K slab to LDS as fp16, once: 16 units per thread ----
#pragma unroll
  for (int u = 0; u < 16; ++u) {
    const int idx = t + 512 * u, jj = idx >> 3, e8 = idx & 7;
    const float4* kp = (const float4*)(Kbh + (size_t)jj * (kH * kE) + e8 * 8);
    const float4 c0 = kp[0], c1 = kp[1];
    Ksh[jj * 8 + (e8 ^ (jj & 7))] =
        make_float4(pk2(c0.x, c0.y), pk2(c0.z, c0.w), pk2(c1.x, c1.y), pk2(c1.z, c1.w));
  }

#pragma unroll 1
  for (int c = 0; c < NCH; ++c) {
    const int l0 = Lbase + c * LT;
    __syncthreads();  // prev chunk's epilogue done (and K staged, first iter)

    if (t < LT) { cnt_s[t] = 0; cnt2_s[t] = 0; }
    if (t >= 384 && t < 512) ((float*)rmax_s)[t - 384] = -1e30f;
    if (t < 256) {  // stage Q chunk: 32 rows x 8 slots of 8 halfs
      const int jj = t >> 3, e8 = t & 7;
      const float4* qp =
          (const float4*)(Q + (((size_t)(b * kL + l0 + jj)) * kH + h) * kE + e8 * 8);
      float4 q0 = qp[0], q1 = qp[1];
      q0.x *= .125f; q0.y *= .125f; q0.z *= .125f; q0.w *= .125f;
      q1.x *= .125f; q1.y *= .125f; q1.z *= .125f; q1.w *= .125f;
      Qsh[jj * 8 + (e8 ^ (jj & 7))] =
          make_float4(pk2(q0.x, q0.y), pk2(q0.z, q0.w), pk2(q1.x, q1.y), pk2(q1.z, q1.w));
    }
    __syncthreads();  // resets + Q visible

    const f16x8 b0 = __builtin_bit_cast(f16x8, Qsh[myrow * 8 + ((0 + g) ^ (myrow & 7))]);
    const f16x8 b1 = __builtin_bit_cast(f16x8, Qsh[myrow * 8 + ((4 + g) ^ (myrow & 7))]);

    float runl = -1e30f;  // per-lane running max over seen scores of myrow

    // ---- j-tile loop: NO barriers, NO staging (K resident) ----
#pragma unroll 1
    for (int jt = 0; jt < kS / JT; ++jt) {
      f32x4 acc[2];
      acc[0] = f32x4{0.f, 0.f, 0.f, 0.f};
      acc[1] = f32x4{0.f, 0.f, 0.f, 0.f};
#pragma unroll
      for (int ct = 0; ct < 2; ++ct) {  // A = K rows (m dim = j)
        const int jrow = jg * 32 + ct * 16 + li;
        const int jabs = jt * JT + jrow;
        const f16x8 a0 = __builtin_bit_cast(f16x8, Ksh[jabs * 8 + ((0 + g) ^ (jrow & 7))]);
        const f16x8 a1 = __builtin_bit_cast(f16x8, Ksh[jabs * 8 + ((4 + g) ^ (jrow & 7))]);
        acc[ct] = __builtin_amdgcn_mfma_f32_16x16x32_f16(a0, b0, acc[ct], 0, 0, 0);
        acc[ct] = __builtin_amdgcn_mfma_f32_16x16x32_f16(a1, b1, acc[ct], 0, 0, 0);
      }
      // D[j = jt*128 + jg*32 + ct*16 + g*4 + reg][query = myrow]

      // ---- filter: per-lane max tree + 2-shuffle quarter reduce ----
      const float m01 = fmaxf(fmaxf(acc[0][0], acc[0][1]), fmaxf(acc[0][2], acc[0][3]));
      const float m23 = fmaxf(fmaxf(acc[1][0], acc[1][1]), fmaxf(acc[1][2], acc[1][3]));
      runl = fmaxf(runl, fmaxf(m01, m23));
      float mr = fmaxf(runl, __shfl_xor(runl, 16));
      mr = fmaxf(mr, __shfl_xor(mr, 32));
      // publish quarter max; read all 4 (monotone, stale only loosens -> safe)
      if (lane < 16) rmax_s[myrow][jg] = mr;
      float rm = fmaxf(fmaxf(rmax_s[myrow][0], rmax_s[myrow][1]),
                       fmaxf(rmax_s[myrow][2], rmax_s[myrow][3]));
      const float thr = fmaxf(rm, mr) - 1.0f;  // <= rowmax-1 <= tau*: superset
      const int jbase = jt * JT + jg * 32 + g * 4;
#pragma unroll
      for (int ct = 0; ct < 2; ++ct)
#pragma unroll
        for (int r = 0; r < 4; ++r) {
          const float z = acc[ct][r];
          if (z > thr) {
            const int pos = atomicAdd(&cnt_s[myrow], 1);
            if (pos < CAP)
              lists[myrow * CAP + pos] =
                  (__float_as_uint(z) & ~1023u) | (unsigned)(jbase + ct * 16 + r);
          }
        }
    }
    __syncthreads();  // lists/cnt/rmax final for this chunk

    // ---- Newton: wave w owns rows w*4..+3; row w*4+g, 16 lanes each ----
    const int q0 = w * 4;
    {
      const int row = q0 + g;
      const int n   = cnt_s[row];
      const int nc  = min(n, CAP);
      float zr[KMAX];
#pragma unroll
      for (int k = 0; k < KMAX; ++k) {
        const int i = li + 16 * k;
        zr[k] = (i < nc) ? unpack_z(lists[row * CAP + i]) : -1e30f;
      }
      const float M =
          fmaxf(fmaxf(rmax_s[row][0], rmax_s[row][1]), fmaxf(rmax_s[row][2], rmax_s[row][3]));
      float t0 = M - 1.0f;
      for (int it = 0; it < 14; ++it) {
        float s = 0.f, cc = 0.f;
#pragma unroll
        for (int k = 0; k < KMAX; ++k) {
          const float d = zr[k] - t0;
          if (d > 0.f) { s += d; cc += 1.f; }
        }
        s += __shfl_xor(s, 1); cc += __shfl_xor(cc, 1);
        s += __shfl_xor(s, 2); cc += __shfl_xor(cc, 2);
        s += __shfl_xor(s, 4); cc += __shfl_xor(cc, 4);
        s += __shfl_xor(s, 8); cc += __shfl_xor(cc, 8);
        const float delta = (s - 1.0f) / fmaxf(cc, 1.f);
        t0 += fmaxf(delta, 0.f);
        if (__all(delta <= 1e-6f)) break;
      }
      if (li == 0) tau_s[row] = t0;
      // compact support: t0 <= tau -> {z > t0} is an exact superset of the
      // support. Same wave writes AND reads sup_s/cnt2_s for its rows.
#pragma unroll
      for (int k = 0; k < KMAX; ++k) {
        const int i = li + 16 * k;
        if (i < nc && zr[k] > t0) {
          const int pos = atomicAdd(&cnt2_s[row], 1);
          if (pos < SUP) sup_s[row][pos] = lists[row * CAP + i];
        }
      }
    }

    // ---- sparse A*V over compacted support, float4 over dims ----
#pragma unroll 1
    for (int r4 = 0; r4 < 4; ++r4) {
      const int row = q0 + r4;
      const int n   = cnt_s[row];
      const size_t obase = (((size_t)(b * kL + l0 + row)) * kH + h) * kD;
      if (n <= CAP) {
        const float tau = tau_s[row];
        const int k2 = cnt2_s[row];
        f32x4 o4 = {0.f, 0.f, 0.f, 0.f};
        if (k2 <= SUP) {
          for (int i = g; i < k2; i += 4) {
            const unsigned e = sup_s[row][i];
            const float  p = fmaxf(unpack_z(e) - tau, 0.f);
            const float4 v =
                ((const float4*)(Vb + (size_t)(e & 1023u) * (kH * kD)))[li];
            o4.x = fmaf(p, v.x, o4.x);
            o4.y = fmaf(p, v.y, o4.y);
            o4.z = fmaf(p, v.z, o4.z);
            o4.w = fmaf(p, v.w, o4.w);
          }
        } else {
          const int nc = n;
          for (int i = g; i < nc; i += 8) {
            const int   i2 = i + 4;
            const bool  ok2 = (i2 < nc);
            const unsigned e1 = lists[row * CAP + i];
            const unsigned e2 = lists[row * CAP + (ok2 ? i2 : i)];
            const float  p1 = fmaxf(unpack_z(e1) - tau, 0.f);
            const float  p2 = ok2 ? fmaxf(unpack_z(e2) - tau, 0.f) : 0.f;
            const float4 v1 =
                ((const float4*)(Vb + (size_t)(e1 & 1023u) * (kH * kD)))[li];
            const float4 v2 =
                ((const float4*)(Vb + (size_t)(e2 & 1023u) * (kH * kD)))[li];
            o4.x = fmaf(p1, v1.x, fmaf(p2, v2.x, o4.x));
            o4.y = fmaf(p1, v1.y, fmaf(p2, v2.y, o4.y));
            o4.z = fmaf(p1, v1.z, fmaf(p2, v2.z, o4.z));
            o4.w = fmaf(p1, v1.w, fmaf(p2, v2.w, o4.w));
          }
        }
        o4.x += __shfl_xor(o4.x, 16); o4.y += __shfl_xor(o4.y, 16);
        o4.z += __shfl_xor(o4.z, 16); o4.w += __shfl_xor(o4.w, 16);
        o4.x += __shfl_xor(o4.x, 32); o4.y += __shfl_xor(o4.y, 32);
        o4.z += __shfl_xor(o4.z, 32); o4.w += __shfl_xor(o4.w, 32);
        if (lane < 16)
          ((float4*)(O + obase))[li] = make_float4(o4.x, o4.y, o4.z, o4.w);
      } else {
        // ---- cold exact fallback (list overflow): dense recompute ----
        float scr2[16];
        for (int cc = 0; cc < 16; ++cc) {
          const int j = lane + 64 * cc;
          const float* kr = Kbh + (size_t)j * (kH * kE);
          float zz = 0.f;
          for (int e8 = 0; e8 < 8; ++e8) {
            const f16x8 qh = __builtin_bit_cast(f16x8, Qsh[row * 8 + (e8 ^ (row & 7))]);
            const float4* kp = (const float4*)(kr + e8 * 8);
            const float4 c0 = kp[0], c1 = kp[1];
            zz += (float)qh[0] * c0.x + (float)qh[1] * c0.y + (float)qh[2] * c0.z +
                  (float)qh[3] * c0.w + (float)qh[4] * c1.x + (float)qh[5] * c1.y +
                  (float)qh[6] * c1.z + (float)qh[7] * c1.w;
          }
          scr2[cc] = zz;
        }
        const float M2 =
            fmaxf(fmaxf(rmax_s[row][0], rmax_s[row][1]), fmaxf(rmax_s[row][2], rmax_s[row][3]));
        float t0 = M2 - 1.0f;
        for (int it = 0; it < 48; ++it) {
          float s = 0.f, cc2 = 0.f;
          for (int cc = 0; cc < 16; ++cc) {
            const float d = scr2[cc] - t0;
            if (d > 0.f) { s += d; cc2 += 1.f; }
          }
          for (int off = 32; off; off >>= 1) { s += __shfl_xor(s, off); cc2 += __shfl_xor(cc2, off); }
          const float delta = (s - 1.0f) / fmaxf(cc2, 1.f);
          if (delta <= 1e-7f) break;
          t0 += delta;
        }
        float oacc = 0.f;
        for (int cc = 0; cc < 16; ++cc)
          for (int src = 0; src < 64; ++src) {
            const float z = __shfl(scr2[cc], src);
            const float p = z - t0;
            if (p > 0.f)
              oacc = fmaf(p, Vb[(size_t)(src + 64 * cc) * (kH * kD) + lane], oacc);
          }
        O[obase + lane] = oacc;
      }
    }
  }
}

extern "C" void kernel_launch(void* const* d_in, const int* in_sizes, int n_in,
                              void* d_out, int out_size, void* d_ws, size_t ws_size,
                              hipStream_t stream) {
  (void)in_sizes; (void)n_in; (void)out_size; (void)d_ws; (void)ws_size;
  const float* Q = (const float*)d_in[0];
  const float* K = (const float*)d_in[1];
  const float* V = (const float*)d_in[2];
  float* O = (float*)d_out;
  sparsemax_attn<<<dim3(kB * kH * 2), dim3(512), 0, stream>>>(Q, K, V, O);
}

// Round 7
// 643.717 us; speedup vs baseline: 1.0600x; 1.0600x over previous
//
#include <hip/hip_runtime.h>

// Sparsemax attention: B=8, L=1024, S=1024, H=16, E=64, D=64, fp32 in/out.
// r16 = barrier-free main loop: K MFMA fragments loaded global->reg directly
// (r10's structure) with the spill fixed (r10 failed on VGPR clamp vs the
// CAP=192/KMAX=12 epilogue; now KMAX=7 + SUP compaction, bounds(512,6) ->
// VGPR<=85, 3 blocks/CU = 24 waves). 2 barriers per block (was 18).
// Evidence: 8 waves->710us, 16->432, 32->329; at the wave cap the floor is
// per-wave latency (VALUBusy ~31% max) -- so cut the chains: no staging
// convoy, no per-tile barriers, stale-rm read hoisted to tile top (monotone
// rmax sharing is barrier-free safe). Epilogue identical to r14.

typedef _Float16 f16x8 __attribute__((ext_vector_type(8)));
typedef float    f32x4 __attribute__((ext_vector_type(4)));

constexpr int kB = 8, kL = 1024, kS = 1024, kH = 16, kE = 64, kD = 64;
constexpr int LT   = 32;          // L rows per block (2 query-groups of 16)
constexpr int JT   = 128;         // S cols per j-tile
constexpr int CAP  = 112;         // candidate capacity per row
constexpr int KMAX = CAP / 16;    // Newton regs per lane (16 lanes per row)
constexpr int SUP  = 24;          // compacted support capacity per row

__device__ __forceinline__ float pk2(float a, float b) {
  auto h = __builtin_amdgcn_cvt_pkrtz(a, b);
  return __builtin_bit_cast(float, h);
}

__device__ __forceinline__ float unpack_z(unsigned v) {
  return __uint_as_float((v & ~1023u) | 512u);  // midpoint restore
}

// 8 fp32 -> f16x8 fragment (2x float4 global load + pack), same numerics as
// the staged path (cvt_pkrtz both ways).
__device__ __forceinline__ f16x8 ldk8(const float* __restrict__ p) {
  const float4 c0 = ((const float4*)p)[0], c1 = ((const float4*)p)[1];
  const float4 r = make_float4(pk2(c0.x, c0.y), pk2(c0.z, c0.w),
                               pk2(c1.x, c1.y), pk2(c1.z, c1.w));
  return __builtin_bit_cast(f16x8, r);
}

__global__ __launch_bounds__(512, 6)   // VGPR<=85 -> 3 blocks/CU (24 waves)
void sparsemax_attn(const float* __restrict__ Q, const float* __restrict__ K,
                    const float* __restrict__ V, float* __restrict__ O) {
  __shared__ float4   Qsh[LT * 8];      //  4 KB fp16 Q tile (scale folded)
  __shared__ unsigned lists[LT * CAP];  // 14 KB packed (z-hi22 | j10)
  __shared__ unsigned sup_s[LT][SUP];   //  3 KB compacted support entries
  __shared__ int      cnt_s[LT];
  __shared__ int      cnt2_s[LT];
  __shared__ float    rmax_s[LT][4];
  __shared__ float    tau_s[LT];

  const int t = threadIdx.x, lane = t & 63, w = t >> 6;
  const int qg = w >> 2, jg = w & 3;       // query-group, j-group
  const int li = lane & 15, g = lane >> 4;
  const int myrow = qg * 16 + li;          // the ONE output row this lane serves

  // XCD-aware remap: round-robin id%8 -> XCD; same-XCD blocks share few bh.
  const int id  = blockIdx.x;              // 4096 blocks
  const int xcd = id & 7, kk = id >> 3;
  const int bh  = xcd * 16 + (kk >> 5);    // 16 bh per XCD, slow-varying
  const int b   = bh >> 4, h = bh & 15;
  const int l0  = (kk & 31) * LT;

  const float* Kbh = K + ((size_t)b * kS * kH + h) * kE;
  const float* Vb  = V + ((size_t)b * kS * kH + h) * kD;

  if (t < LT) { cnt_s[t] = 0; cnt2_s[t] = 0; }
  if (t >= 384 && t < 512) ((float*)rmax_s)[t - 384] = -1e30f;  // init quarters
  if (t < 256) {  // stage Q: 32 rows x 8 slots of 8 halfs
    const int jj = t >> 3, e8 = t & 7;
    const float4* qp =
        (const float4*)(Q + (((size_t)(b * kL + l0 + jj)) * kH + h) * kE + e8 * 8);
    float4 q0 = qp[0], q1 = qp[1];
    q0.x *= .125f; q0.y *= .125f; q0.z *= .125f; q0.w *= .125f;
    q1.x *= .125f; q1.y *= .125f; q1.z *= .125f; q1.w *= .125f;
    Qsh[jj * 8 + (e8 ^ (jj & 7))] =
        make_float4(pk2(q0.x, q0.y), pk2(q0.z, q0.w), pk2(q1.x, q1.y), pk2(q1.z, q1.w));
  }
  __syncthreads();  // Qsh + inits visible; barrier #1 of 2

  // B-frags: Q[row = myrow][k-chunks g, 4+g] (k-contiguous)
  const f16x8 b0 = __builtin_bit_cast(f16x8, Qsh[myrow * 8 + ((0 + g) ^ (myrow & 7))]);
  const f16x8 b1 = __builtin_bit_cast(f16x8, Qsh[myrow * 8 + ((4 + g) ^ (myrow & 7))]);

  // Per-lane K fragment base: A rows jl = jg*32 + ct*16 + li, chunks {g, 4+g}.
  const float* Klane = Kbh + (size_t)(jg * 32 + li) * (kH * kE) + g * 8;

  float runl = -1e30f;    // per-lane cumulative max over seen scores of myrow

#pragma unroll 1
  for (int jt = 0; jt < kS / JT; ++jt) {
    // stale quarter-max read hoisted to tile top: LDS latency hides under
    // the K loads below. Monotone values -> staleness only loosens (safe).
    const float rm_st = fmaxf(fmaxf(rmax_s[myrow][0], rmax_s[myrow][1]),
                              fmaxf(rmax_s[myrow][2], rmax_s[myrow][3]));

    const float* kt = Klane + (size_t)jt * JT * (kH * kE);
    f32x4 acc[2];
    acc[0] = f32x4{0.f, 0.f, 0.f, 0.f};
    acc[1] = f32x4{0.f, 0.f, 0.f, 0.f};
#pragma unroll
    for (int ct = 0; ct < 2; ++ct) {  // A = K rows (m dim = j), global->reg
      const float* kr = kt + (size_t)ct * 16 * (kH * kE);
      const f16x8 a0 = ldk8(kr);        // chunk g
      const f16x8 a1 = ldk8(kr + 32);   // chunk 4+g
      acc[ct] = __builtin_amdgcn_mfma_f32_16x16x32_f16(a0, b0, acc[ct], 0, 0, 0);
      acc[ct] = __builtin_amdgcn_mfma_f32_16x16x32_f16(a1, b1, acc[ct], 0, 0, 0);
    }
    // D[j = jt*128 + jg*32 + ct*16 + g*4 + reg][query = myrow]

    // ---- filter: per-lane max tree + 2-shuffle quarter reduce ----
    const float m01 = fmaxf(fmaxf(acc[0][0], acc[0][1]), fmaxf(acc[0][2], acc[0][3]));
    const float m23 = fmaxf(fmaxf(acc[1][0], acc[1][1]), fmaxf(acc[1][2], acc[1][3]));
    runl = fmaxf(runl, fmaxf(m01, m23));
    float mr = fmaxf(runl, __shfl_xor(runl, 16));
    mr = fmaxf(mr, __shfl_xor(mr, 32));
    if (lane < 16) rmax_s[myrow][jg] = mr;   // publish (monotone)
    const float thr = fmaxf(rm_st, mr) - 1.0f;  // <= rowmax-1 <= tau*: superset
    const int jbase = jt * JT + jg * 32 + g * 4;
#pragma unroll
    for (int ct = 0; ct < 2; ++ct)
#pragma unroll
      for (int r = 0; r < 4; ++r) {
        const float z = acc[ct][r];
        if (z > thr) {
          const int pos = atomicAdd(&cnt_s[myrow], 1);
          if (pos < CAP)
            lists[myrow * CAP + pos] =
                (__float_as_uint(z) & ~1023u) | (unsigned)(jbase + ct * 16 + r);
        }
      }
  }
  __syncthreads();  // lists/cnt/rmax final; barrier #2 of 2

  // ---- Newton: wave w owns rows w*4..+3; row w*4+g, 16 lanes each ----
  const int q0 = w * 4;
  {
    const int row = q0 + g;
    const int n   = cnt_s[row];
    const int nc  = min(n, CAP);
    float zr[KMAX];
#pragma unroll
    for (int k = 0; k < KMAX; ++k) {
      const int i = li + 16 * k;
      zr[k] = (i < nc) ? unpack_z(lists[row * CAP + i]) : -1e30f;
    }
    const float M =
        fmaxf(fmaxf(rmax_s[row][0], rmax_s[row][1]), fmaxf(rmax_s[row][2], rmax_s[row][3]));
    float t0 = M - 1.0f;
    for (int it = 0; it < 14; ++it) {
      float s = 0.f, c = 0.f;
#pragma unroll
      for (int k = 0; k < KMAX; ++k) {
        const float d = zr[k] - t0;
        if (d > 0.f) { s += d; c += 1.f; }
      }
      s += __shfl_xor(s, 1); c += __shfl_xor(c, 1);
      s += __shfl_xor(s, 2); c += __shfl_xor(c, 2);
      s += __shfl_xor(s, 4); c += __shfl_xor(c, 4);
      s += __shfl_xor(s, 8); c += __shfl_xor(c, 8);
      const float delta = (s - 1.0f) / fmaxf(c, 1.f);
      t0 += fmaxf(delta, 0.f);
      if (__all(delta <= 1e-6f)) break;
    }
    if (li == 0) tau_s[row] = t0;
    // compact support: t0 <= tau -> {z > t0} is an exact superset of the
    // support. Same wave writes AND reads sup_s/cnt2_s for its rows.
#pragma unroll
    for (int k = 0; k < KMAX; ++k) {
      const int i = li + 16 * k;
      if (i < nc && zr[k] > t0) {
        const int pos = atomicAdd(&cnt2_s[row], 1);
        if (pos < SUP) sup_s[row][pos] = lists[row * CAP + i];
      }
    }
  }

  // ---- sparse A*V over compacted support, float4 over dims ----
#pragma unroll 1
  for (int r4 = 0; r4 < 4; ++r4) {
    const int row = q0 + r4;
    const int n   = cnt_s[row];
    const size_t obase = (((size_t)(b * kL + l0 + row)) * kH + h) * kD;
    if (n <= CAP) {
      const float tau = tau_s[row];
      const int k2 = cnt2_s[row];
      f32x4 o4 = {0.f, 0.f, 0.f, 0.f};
      if (k2 <= SUP) {
        for (int i = g; i < k2; i += 4) {
          const unsigned e = sup_s[row][i];
          const float  p = fmaxf(unpack_z(e) - tau, 0.f);
          const float4 v =
              ((const float4*)(Vb + (size_t)(e & 1023u) * (kH * kD)))[li];
          o4.x = fmaf(p, v.x, o4.x);
          o4.y = fmaf(p, v.y, o4.y);
          o4.z = fmaf(p, v.z, o4.z);
          o4.w = fmaf(p, v.w, o4.w);
        }
      } else {
        const int nc = n;
        for (int i = g; i < nc; i += 8) {
          const int   i2 = i + 4;
          const bool  ok2 = (i2 < nc);
          const unsigned e1 = lists[row * CAP + i];
          const unsigned e2 = lists[row * CAP + (ok2 ? i2 : i)];
          const float  p1 = fmaxf(unpack_z(e1) - tau, 0.f);
          const float  p2 = ok2 ? fmaxf(unpack_z(e2) - tau, 0.f) : 0.f;
          const float4 v1 =
              ((const float4*)(Vb + (size_t)(e1 & 1023u) * (kH * kD)))[li];
          const float4 v2 =
              ((const float4*)(Vb + (size_t)(e2 & 1023u) * (kH * kD)))[li];
          o4.x = fmaf(p1, v1.x, fmaf(p2, v2.x, o4.x));
          o4.y = fmaf(p1, v1.y, fmaf(p2, v2.y, o4.y));
          o4.z = fmaf(p1, v1.z, fmaf(p2, v2.z, o4.z));
          o4.w = fmaf(p1, v1.w, fmaf(p2, v2.w, o4.w));
        }
      }
      o4.x += __shfl_xor(o4.x, 16); o4.y += __shfl_xor(o4.y, 16);
      o4.z += __shfl_xor(o4.z, 16); o4.w += __shfl_xor(o4.w, 16);
      o4.x += __shfl_xor(o4.x, 32); o4.y += __shfl_xor(o4.y, 32);
      o4.z += __shfl_xor(o4.z, 32); o4.w += __shfl_xor(o4.w, 32);
      if (lane < 16)
        ((float4*)(O + obase))[li] = make_float4(o4.x, o4.y, o4.z, o4.w);
    } else {
      // ---- cold exact fallback (list overflow): dense recompute ----
      float scr2[16];
      for (int cc = 0; cc < 16; ++cc) {
        const int j = lane + 64 * cc;
        const float* kr = Kbh + (size_t)j * (kH * kE);
        float zz = 0.f;
        for (int e8 = 0; e8 < 8; ++e8) {
          const f16x8 qh = __builtin_bit_cast(f16x8, Qsh[row * 8 + (e8 ^ (row & 7))]);
          const float4* kp = (const float4*)(kr + e8 * 8);
          const float4 c0 = kp[0], c1 = kp[1];
          zz += (float)qh[0] * c0.x + (float)qh[1] * c0.y + (float)qh[2] * c0.z +
                (float)qh[3] * c0.w + (float)qh[4] * c1.x + (float)qh[5] * c1.y +
                (float)qh[6] * c1.z + (float)qh[7] * c1.w;
        }
        scr2[cc] = zz;
      }
      const float M2 =
          fmaxf(fmaxf(rmax_s[row][0], rmax_s[row][1]), fmaxf(rmax_s[row][2], rmax_s[row][3]));
      float t0 = M2 - 1.0f;
      for (int it = 0; it < 48; ++it) {
        float s = 0.f, c = 0.f;
        for (int cc = 0; cc < 16; ++cc) {
          const float d = scr2[cc] - t0;
          if (d > 0.f) { s += d; c += 1.f; }
        }
        for (int off = 32; off; off >>= 1) { s += __shfl_xor(s, off); c += __shfl_xor(c, off); }
        const float delta = (s - 1.0f) / fmaxf(c, 1.f);
        if (delta <= 1e-7f) break;
        t0 += delta;
      }
      float oacc = 0.f;
      for (int cc = 0; cc < 16; ++cc)
        for (int src = 0; src < 64; ++src) {
          const float z = __shfl(scr2[cc], src);
          const float p = z - t0;
          if (p > 0.f)
            oacc = fmaf(p, Vb[(size_t)(src + 64 * cc) * (kH * kD) + lane], oacc);
        }
      O[obase + lane] = oacc;
    }
  }
}

extern "C" void kernel_launch(void* const* d_in, const int* in_sizes, int n_in,
                              void* d_out, int out_size, void* d_ws, size_t ws_size,
                              hipStream_t stream) {
  (void)in_sizes; (void)n_in; (void)out_size; (void)d_ws; (void)ws_size;
  const float* Q = (const float*)d_in[0];
  const float* K = (const float*)d_in[1];
  const float* V = (const float*)d_in[2];
  float* O = (float*)d_out;
  sparsemax_attn<<<dim3(kB * kH * (kL / LT)), dim3(512), 0, stream>>>(Q, K, V, O);
}

// Round 8
// 512.655 us; speedup vs baseline: 1.3310x; 1.2557x over previous
//
#include <hip/hip_runtime.h>

// Sparsemax attention: B=8, L=1024, S=1024, H=16, E=64, D=64, fp32 in/out.
// r17 = r16 (barrier-free K-direct main loop) with launch_bounds (512,4).
// Diagnosis: r10/r16 both spilled ONLY because (512,6) clamped VGPR to 40
// (636MB scratch writeback); the K-direct structure was never tested
// unspilled. (512,4) = cap 128; epilogue compiles to 64 in r12/r14 and
// main-loop/epilogue liveness doesn't overlap -> expect ~64-84 natural.
// If <=64: 4 blocks/CU (32-wave cap) AND zero per-tile barriers AND zero
// staging work -- all identified levers simultaneously.
// Structure: 2 barriers per block total; K MFMA fragments global->reg
// (L2-resident slab, XCD remap); monotone cross-wave rmax sharing with
// stale-read hoisted to tile top; packed u32 lists; Newton + support
// compaction + compacted gather identical to r14.

typedef _Float16 f16x8 __attribute__((ext_vector_type(8)));
typedef float    f32x4 __attribute__((ext_vector_type(4)));

constexpr int kB = 8, kL = 1024, kS = 1024, kH = 16, kE = 64, kD = 64;
constexpr int LT   = 32;          // L rows per block (2 query-groups of 16)
constexpr int JT   = 128;         // S cols per j-tile
constexpr int CAP  = 112;         // candidate capacity per row
constexpr int KMAX = CAP / 16;    // Newton regs per lane (16 lanes per row)
constexpr int SUP  = 24;          // compacted support capacity per row

__device__ __forceinline__ float pk2(float a, float b) {
  auto h = __builtin_amdgcn_cvt_pkrtz(a, b);
  return __builtin_bit_cast(float, h);
}

__device__ __forceinline__ float unpack_z(unsigned v) {
  return __uint_as_float((v & ~1023u) | 512u);  // midpoint restore
}

// 8 fp32 -> f16x8 fragment (2x float4 global load + pack), same numerics as
// the staged path (cvt_pkrtz both ways).
__device__ __forceinline__ f16x8 ldk8(const float* __restrict__ p) {
  const float4 c0 = ((const float4*)p)[0], c1 = ((const float4*)p)[1];
  const float4 r = make_float4(pk2(c0.x, c0.y), pk2(c0.z, c0.w),
                               pk2(c1.x, c1.y), pk2(c1.z, c1.w));
  return __builtin_bit_cast(f16x8, r);
}

__global__ __launch_bounds__(512, 4)   // cap 128 VGPR: NO forced clamp/spill
void sparsemax_attn(const float* __restrict__ Q, const float* __restrict__ K,
                    const float* __restrict__ V, float* __restrict__ O) {
  __shared__ float4   Qsh[LT * 8];      //  4 KB fp16 Q tile (scale folded)
  __shared__ unsigned lists[LT * CAP];  // 14 KB packed (z-hi22 | j10)
  __shared__ unsigned sup_s[LT][SUP];   //  3 KB compacted support entries
  __shared__ int      cnt_s[LT];
  __shared__ int      cnt2_s[LT];
  __shared__ float    rmax_s[LT][4];
  __shared__ float    tau_s[LT];

  const int t = threadIdx.x, lane = t & 63, w = t >> 6;
  const int qg = w >> 2, jg = w & 3;       // query-group, j-group
  const int li = lane & 15, g = lane >> 4;
  const int myrow = qg * 16 + li;          // the ONE output row this lane serves

  // XCD-aware remap: round-robin id%8 -> XCD; same-XCD blocks share few bh.
  const int id  = blockIdx.x;              // 4096 blocks
  const int xcd = id & 7, kk = id >> 3;
  const int bh  = xcd * 16 + (kk >> 5);    // 16 bh per XCD, slow-varying
  const int b   = bh >> 4, h = bh & 15;
  const int l0  = (kk & 31) * LT;

  const float* Kbh = K + ((size_t)b * kS * kH + h) * kE;
  const float* Vb  = V + ((size_t)b * kS * kH + h) * kD;

  if (t < LT) { cnt_s[t] = 0; cnt2_s[t] = 0; }
  if (t >= 384 && t < 512) ((float*)rmax_s)[t - 384] = -1e30f;  // init quarters
  if (t < 256) {  // stage Q: 32 rows x 8 slots of 8 halfs
    const int jj = t >> 3, e8 = t & 7;
    const float4* qp =
        (const float4*)(Q + (((size_t)(b * kL + l0 + jj)) * kH + h) * kE + e8 * 8);
    float4 q0 = qp[0], q1 = qp[1];
    q0.x *= .125f; q0.y *= .125f; q0.z *= .125f; q0.w *= .125f;
    q1.x *= .125f; q1.y *= .125f; q1.z *= .125f; q1.w *= .125f;
    Qsh[jj * 8 + (e8 ^ (jj & 7))] =
        make_float4(pk2(q0.x, q0.y), pk2(q0.z, q0.w), pk2(q1.x, q1.y), pk2(q1.z, q1.w));
  }
  __syncthreads();  // Qsh + inits visible; barrier #1 of 2

  // B-frags: Q[row = myrow][k-chunks g, 4+g] (k-contiguous)
  const f16x8 b0 = __builtin_bit_cast(f16x8, Qsh[myrow * 8 + ((0 + g) ^ (myrow & 7))]);
  const f16x8 b1 = __builtin_bit_cast(f16x8, Qsh[myrow * 8 + ((4 + g) ^ (myrow & 7))]);

  // Per-lane K fragment base: A rows jl = jg*32 + ct*16 + li, chunks {g, 4+g}.
  const float* Klane = Kbh + (size_t)(jg * 32 + li) * (kH * kE) + g * 8;

  float runl = -1e30f;    // per-lane cumulative max over seen scores of myrow

#pragma unroll 1
  for (int jt = 0; jt < kS / JT; ++jt) {
    // stale quarter-max read hoisted to tile top: LDS latency hides under
    // the K loads below. Monotone values -> staleness only loosens (safe).
    const float rm_st = fmaxf(fmaxf(rmax_s[myrow][0], rmax_s[myrow][1]),
                              fmaxf(rmax_s[myrow][2], rmax_s[myrow][3]));

    const float* kt = Klane + (size_t)jt * JT * (kH * kE);
    f32x4 acc[2];
    acc[0] = f32x4{0.f, 0.f, 0.f, 0.f};
    acc[1] = f32x4{0.f, 0.f, 0.f, 0.f};
#pragma unroll
    for (int ct = 0; ct < 2; ++ct) {  // A = K rows (m dim = j), global->reg
      const float* kr = kt + (size_t)ct * 16 * (kH * kE);
      const f16x8 a0 = ldk8(kr);        // chunk g
      const f16x8 a1 = ldk8(kr + 32);   // chunk 4+g
      acc[ct] = __builtin_amdgcn_mfma_f32_16x16x32_f16(a0, b0, acc[ct], 0, 0, 0);
      acc[ct] = __builtin_amdgcn_mfma_f32_16x16x32_f16(a1, b1, acc[ct], 0, 0, 0);
    }
    // D[j = jt*128 + jg*32 + ct*16 + g*4 + reg][query = myrow]

    // ---- filter: per-lane max tree + 2-shuffle quarter reduce ----
    const float m01 = fmaxf(fmaxf(acc[0][0], acc[0][1]), fmaxf(acc[0][2], acc[0][3]));
    const float m23 = fmaxf(fmaxf(acc[1][0], acc[1][1]), fmaxf(acc[1][2], acc[1][3]));
    runl = fmaxf(runl, fmaxf(m01, m23));
    float mr = fmaxf(runl, __shfl_xor(runl, 16));
    mr = fmaxf(mr, __shfl_xor(mr, 32));
    if (lane < 16) rmax_s[myrow][jg] = mr;   // publish (monotone)
    const float thr = fmaxf(rm_st, mr) - 1.0f;  // <= rowmax-1 <= tau*: superset
    const int jbase = jt * JT + jg * 32 + g * 4;
#pragma unroll
    for (int ct = 0; ct < 2; ++ct)
#pragma unroll
      for (int r = 0; r < 4; ++r) {
        const float z = acc[ct][r];
        if (z > thr) {
          const int pos = atomicAdd(&cnt_s[myrow], 1);
          if (pos < CAP)
            lists[myrow * CAP + pos] =
                (__float_as_uint(z) & ~1023u) | (unsigned)(jbase + ct * 16 + r);
        }
      }
  }
  __syncthreads();  // lists/cnt/rmax final; barrier #2 of 2

  // ---- Newton: wave w owns rows w*4..+3; row w*4+g, 16 lanes each ----
  const int q0 = w * 4;
  {
    const int row = q0 + g;
    const int n   = cnt_s[row];
    const int nc  = min(n, CAP);
    float zr[KMAX];
#pragma unroll
    for (int k = 0; k < KMAX; ++k) {
      const int i = li + 16 * k;
      zr[k] = (i < nc) ? unpack_z(lists[row * CAP + i]) : -1e30f;
    }
    const float M =
        fmaxf(fmaxf(rmax_s[row][0], rmax_s[row][1]), fmaxf(rmax_s[row][2], rmax_s[row][3]));
    float t0 = M - 1.0f;
    for (int it = 0; it < 14; ++it) {
      float s = 0.f, c = 0.f;
#pragma unroll
      for (int k = 0; k < KMAX; ++k) {
        const float d = zr[k] - t0;
        if (d > 0.f) { s += d; c += 1.f; }
      }
      s += __shfl_xor(s, 1); c += __shfl_xor(c, 1);
      s += __shfl_xor(s, 2); c += __shfl_xor(c, 2);
      s += __shfl_xor(s, 4); c += __shfl_xor(c, 4);
      s += __shfl_xor(s, 8); c += __shfl_xor(c, 8);
      const float delta = (s - 1.0f) / fmaxf(c, 1.f);
      t0 += fmaxf(delta, 0.f);
      if (__all(delta <= 1e-6f)) break;
    }
    if (li == 0) tau_s[row] = t0;
    // compact support: t0 <= tau -> {z > t0} is an exact superset of the
    // support. Same wave writes AND reads sup_s/cnt2_s for its rows.
#pragma unroll
    for (int k = 0; k < KMAX; ++k) {
      const int i = li + 16 * k;
      if (i < nc && zr[k] > t0) {
        const int pos = atomicAdd(&cnt2_s[row], 1);
        if (pos < SUP) sup_s[row][pos] = lists[row * CAP + i];
      }
    }
  }

  // ---- sparse A*V over compacted support, float4 over dims ----
#pragma unroll 1
  for (int r4 = 0; r4 < 4; ++r4) {
    const int row = q0 + r4;
    const int n   = cnt_s[row];
    const size_t obase = (((size_t)(b * kL + l0 + row)) * kH + h) * kD;
    if (n <= CAP) {
      const float tau = tau_s[row];
      const int k2 = cnt2_s[row];
      f32x4 o4 = {0.f, 0.f, 0.f, 0.f};
      if (k2 <= SUP) {
        for (int i = g; i < k2; i += 4) {
          const unsigned e = sup_s[row][i];
          const float  p = fmaxf(unpack_z(e) - tau, 0.f);
          const float4 v =
              ((const float4*)(Vb + (size_t)(e & 1023u) * (kH * kD)))[li];
          o4.x = fmaf(p, v.x, o4.x);
          o4.y = fmaf(p, v.y, o4.y);
          o4.z = fmaf(p, v.z, o4.z);
          o4.w = fmaf(p, v.w, o4.w);
        }
      } else {
        const int nc = n;
        for (int i = g; i < nc; i += 8) {
          const int   i2 = i + 4;
          const bool  ok2 = (i2 < nc);
          const unsigned e1 = lists[row * CAP + i];
          const unsigned e2 = lists[row * CAP + (ok2 ? i2 : i)];
          const float  p1 = fmaxf(unpack_z(e1) - tau, 0.f);
          const float  p2 = ok2 ? fmaxf(unpack_z(e2) - tau, 0.f) : 0.f;
          const float4 v1 =
              ((const float4*)(Vb + (size_t)(e1 & 1023u) * (kH * kD)))[li];
          const float4 v2 =
              ((const float4*)(Vb + (size_t)(e2 & 1023u) * (kH * kD)))[li];
          o4.x = fmaf(p1, v1.x, fmaf(p2, v2.x, o4.x));
          o4.y = fmaf(p1, v1.y, fmaf(p2, v2.y, o4.y));
          o4.z = fmaf(p1, v1.z, fmaf(p2, v2.z, o4.z));
          o4.w = fmaf(p1, v1.w, fmaf(p2, v2.w, o4.w));
        }
      }
      o4.x += __shfl_xor(o4.x, 16); o4.y += __shfl_xor(o4.y, 16);
      o4.z += __shfl_xor(o4.z, 16); o4.w += __shfl_xor(o4.w, 16);
      o4.x += __shfl_xor(o4.x, 32); o4.y += __shfl_xor(o4.y, 32);
      o4.z += __shfl_xor(o4.z, 32); o4.w += __shfl_xor(o4.w, 32);
      if (lane < 16)
        ((float4*)(O + obase))[li] = make_float4(o4.x, o4.y, o4.z, o4.w);
    } else {
      // ---- cold exact fallback (list overflow): dense recompute ----
      float scr2[16];
      for (int cc = 0; cc < 16; ++cc) {
        const int j = lane + 64 * cc;
        const float* kr = Kbh + (size_t)j * (kH * kE);
        float zz = 0.f;
        for (int e8 = 0; e8 < 8; ++e8) {
          const f16x8 qh = __builtin_bit_cast(f16x8, Qsh[row * 8 + (e8 ^ (row & 7))]);
          const float4* kp = (const float4*)(kr + e8 * 8);
          const float4 c0 = kp[0], c1 = kp[1];
          zz += (float)qh[0] * c0.x + (float)qh[1] * c0.y + (float)qh[2] * c0.z +
                (float)qh[3] * c0.w + (float)qh[4] * c1.x + (float)qh[5] * c1.y +
                (float)qh[6] * c1.z + (float)qh[7] * c1.w;
        }
        scr2[cc] = zz;
      }
      const float M2 =
          fmaxf(fmaxf(rmax_s[row][0], rmax_s[row][1]), fmaxf(rmax_s[row][2], rmax_s[row][3]));
      float t0 = M2 - 1.0f;
      for (int it = 0; it < 48; ++it) {
        float s = 0.f, c = 0.f;
        for (int cc = 0; cc < 16; ++cc) {
          const float d = scr2[cc] - t0;
          if (d > 0.f) { s += d; c += 1.f; }
        }
        for (int off = 32; off; off >>= 1) { s += __shfl_xor(s, off); c += __shfl_xor(c, off); }
        const float delta = (s - 1.0f) / fmaxf(c, 1.f);
        if (delta <= 1e-7f) break;
        t0 += delta;
      }
      float oacc = 0.f;
      for (int cc = 0; cc < 16; ++cc)
        for (int src = 0; src < 64; ++src) {
          const float z = __shfl(scr2[cc], src);
          const float p = z - t0;
          if (p > 0.f)
            oacc = fmaf(p, Vb[(size_t)(src + 64 * cc) * (kH * kD) + lane], oacc);
        }
      O[obase + lane] = oacc;
    }
  }
}

extern "C" void kernel_launch(void* const* d_in, const int* in_sizes, int n_in,
                              void* d_out, int out_size, void* d_ws, size_t ws_size,
                              hipStream_t stream) {
  (void)in_sizes; (void)n_in; (void)out_size; (void)d_ws; (void)ws_size;
  const float* Q = (const float*)d_in[0];
  const float* K = (const float*)d_in[1];
  const float* V = (const float*)d_in[2];
  float* O = (float*)d_out;
  sparsemax_attn<<<dim3(kB * kH * (kL / LT)), dim3(512), 0, stream>>>(Q, K, V, O);
}